// Round 3
// baseline (483.854 us; speedup 1.0000x reference)
//
#include <hip/hip_runtime.h>

// Fused Canny-style edge pipeline, 1x3x4096x4096 fp32 -> 1x4096x4096 fp32.
// R3: interior fast-path (no bounds masks for 97% of blocks), per-channel
// gx/gy accumulated in LDS (reference reduction order), channel loop unrolled.

#define IMG_H 4096
#define IMG_W 4096

constexpr int TW = 32, TH = 32;
constexpr int HBH = 40, HBW = 40;  // hblur:   (r,c) -> abs (Y0-4+r, X0-2+c)
constexpr int BH  = 36, BW  = 40;  // blurred: (r,c) -> abs (Y0-2+r, X0-2+c)
constexpr int MH  = 34, MW  = 36;  // mag/gx/gy: (r,c) -> abs (Y0-1+r, X0-1+c)

struct Smem {
  float hb[HBH * HBW];  // per-channel horizontal blur (transient)
  float bl[BH * BW];    // per-channel blurred (transient)
  float mg[MH * MW];    // grad_mag summed over channels
  float gx[MH * MW];    // sum_ch gx_c
  float gy[MH * MW];    // sum_ch gy_c
};

template <bool INTERIOR>
__device__ __forceinline__ void run_stages(Smem& sm, const float* __restrict__ img,
                                           int X0, int Y0, int tid,
                                           float g0, float g1, float g2, float g3, float g4) {
#pragma unroll
  for (int ch = 0; ch < 3; ++ch) {
    const float* im = img + (size_t)ch * ((size_t)IMG_H * IMG_W);

    // ---- Stage A: horizontal gaussian (40 rows x 10 groups of 4 cols).
    for (int j = tid; j < HBH * 10; j += 256) {
      int r = j / 10, g = j - r * 10, c0 = g * 4;
      float4 o;
      if (INTERIOR) {
        const float* row = im + (size_t)(Y0 - 4 + r) * IMG_W + (X0 - 4 + c0);
        float4 va = *(const float4*)row;
        float4 vb = *(const float4*)(row + 4);
        o.x = g0*va.x + g1*va.y + g2*va.z + g3*va.w + g4*vb.x;
        o.y = g0*va.y + g1*va.z + g2*va.w + g3*vb.x + g4*vb.y;
        o.z = g0*va.z + g1*va.w + g2*vb.x + g3*vb.y + g4*vb.z;
        o.w = g0*va.w + g1*vb.x + g2*vb.y + g3*vb.z + g4*vb.w;
      } else {
        int gy_ = Y0 - 4 + r;
        if ((unsigned)gy_ < IMG_H) {
          int cb = X0 - 4 + c0;
          const float* row = im + (size_t)gy_ * IMG_W;
          float t[8];
#pragma unroll
          for (int u = 0; u < 8; ++u) {
            int x = cb + u;
            t[u] = ((unsigned)x < IMG_W) ? row[x] : 0.f;
          }
          o.x = g0*t[0] + g1*t[1] + g2*t[2] + g3*t[3] + g4*t[4];
          o.y = g0*t[1] + g1*t[2] + g2*t[3] + g3*t[4] + g4*t[5];
          o.z = g0*t[2] + g1*t[3] + g2*t[4] + g3*t[5] + g4*t[6];
          o.w = g0*t[3] + g1*t[4] + g2*t[5] + g3*t[6] + g4*t[7];
        } else {
          o = make_float4(0.f, 0.f, 0.f, 0.f);
        }
      }
      *(float4*)&sm.hb[r * HBW + c0] = o;
    }
    __syncthreads();

    // ---- Stage B: vertical gaussian (36 rows x 10 groups).
    for (int j = tid; j < BH * 10; j += 256) {
      int r = j / 10, g = j - r * 10, c0 = g * 4;
      float4 a0 = *(const float4*)&sm.hb[(r    ) * HBW + c0];
      float4 a1 = *(const float4*)&sm.hb[(r + 1) * HBW + c0];
      float4 a2 = *(const float4*)&sm.hb[(r + 2) * HBW + c0];
      float4 a3 = *(const float4*)&sm.hb[(r + 3) * HBW + c0];
      float4 a4 = *(const float4*)&sm.hb[(r + 4) * HBW + c0];
      float4 v;
      v.x = g0*a0.x + g1*a1.x + g2*a2.x + g3*a3.x + g4*a4.x;
      v.y = g0*a0.y + g1*a1.y + g2*a2.y + g3*a3.y + g4*a4.y;
      v.z = g0*a0.z + g1*a1.z + g2*a2.z + g3*a3.z + g4*a4.z;
      v.w = g0*a0.w + g1*a1.w + g2*a2.w + g3*a3.w + g4*a4.w;
      if (!INTERIOR) {
        // Force exact 0 outside image: the Sobel conv zero-pads *blurred*.
        int gy_ = Y0 - 2 + r;
        bool rok = (unsigned)gy_ < IMG_H;
        int gx0 = X0 - 2 + c0;
        v.x = (rok && (unsigned)(gx0    ) < IMG_W) ? v.x : 0.f;
        v.y = (rok && (unsigned)(gx0 + 1) < IMG_W) ? v.y : 0.f;
        v.z = (rok && (unsigned)(gx0 + 2) < IMG_W) ? v.z : 0.f;
        v.w = (rok && (unsigned)(gx0 + 3) < IMG_W) ? v.w : 0.f;
      }
      *(float4*)&sm.bl[r * BW + c0] = v;
    }
    __syncthreads();

    // ---- Stage C: Sobel + magnitude; accumulate mag/gx/gy (34 rows x 9 groups).
    for (int j = tid; j < MH * 9; j += 256) {
      int r = j / 9, g = j - r * 9, c0 = g * 4;
      float w0[6], w1[6], w2[6];
      {
        float4 p = *(const float4*)&sm.bl[(r    ) * BW + c0];
        float2 q = *(const float2*)&sm.bl[(r    ) * BW + c0 + 4];
        w0[0]=p.x; w0[1]=p.y; w0[2]=p.z; w0[3]=p.w; w0[4]=q.x; w0[5]=q.y;
      }
      {
        float4 p = *(const float4*)&sm.bl[(r + 1) * BW + c0];
        float2 q = *(const float2*)&sm.bl[(r + 1) * BW + c0 + 4];
        w1[0]=p.x; w1[1]=p.y; w1[2]=p.z; w1[3]=p.w; w1[4]=q.x; w1[5]=q.y;
      }
      {
        float4 p = *(const float4*)&sm.bl[(r + 2) * BW + c0];
        float2 q = *(const float2*)&sm.bl[(r + 2) * BW + c0 + 4];
        w2[0]=p.x; w2[1]=p.y; w2[2]=p.z; w2[3]=p.w; w2[4]=q.x; w2[5]=q.y;
      }
      float vgx[4], vgy[4], vmg[4];
#pragma unroll
      for (int e = 0; e < 4; ++e) {
        float gxv = w0[e] - w0[e + 2] + 2.f * w1[e] - 2.f * w1[e + 2] + w2[e] - w2[e + 2];
        float gyv = w0[e] + 2.f * w0[e + 1] + w0[e + 2] - w2[e] - 2.f * w2[e + 1] - w2[e + 2];
        float m = sqrtf(gxv * gxv + gyv * gyv + 1e-8f);
        if (!INTERIOR) {
          int gyy = Y0 - 1 + r, gxx = X0 - 1 + c0 + e;
          m = ((unsigned)gyy < IMG_H && (unsigned)gxx < IMG_W) ? m : 0.f;
        }
        vgx[e] = gxv; vgy[e] = gyv; vmg[e] = m;
      }
      int idx = r * MW + c0;
      if (ch == 0) {
        *(float4*)&sm.mg[idx] = make_float4(vmg[0], vmg[1], vmg[2], vmg[3]);
        *(float4*)&sm.gx[idx] = make_float4(vgx[0], vgx[1], vgx[2], vgx[3]);
        *(float4*)&sm.gy[idx] = make_float4(vgy[0], vgy[1], vgy[2], vgy[3]);
      } else {
        float4 s;
        s = *(float4*)&sm.mg[idx];
        s.x += vmg[0]; s.y += vmg[1]; s.z += vmg[2]; s.w += vmg[3];
        *(float4*)&sm.mg[idx] = s;
        s = *(float4*)&sm.gx[idx];
        s.x += vgx[0]; s.y += vgx[1]; s.z += vgx[2]; s.w += vgx[3];
        *(float4*)&sm.gx[idx] = s;
        s = *(float4*)&sm.gy[idx];
        s.x += vgy[0]; s.y += vgy[1]; s.z += vgy[2]; s.w += vgy[3];
        *(float4*)&sm.gy[idx] = s;
      }
    }
    __syncthreads();
  }
}

__global__ __launch_bounds__(256, 6)
void canny_fused(const float* __restrict__ img,
                 const float* __restrict__ gauss,
                 float* __restrict__ out) {
  __shared__ Smem sm;
  const int tid = threadIdx.x;
  const int X0 = blockIdx.x * TW;
  const int Y0 = blockIdx.y * TH;

  const float g0 = gauss[0], g1 = gauss[1], g2 = gauss[2],
              g3 = gauss[3], g4 = gauss[4];

  const bool interior = (X0 >= 4) && (X0 + 40 <= IMG_W) &&
                        (Y0 >= 4) && (Y0 + 36 <= IMG_H);
  if (interior) run_stages<true>(sm, img, X0, Y0, tid, g0, g1, g2, g3, g4);
  else          run_stages<false>(sm, img, X0, Y0, tid, g0, g1, g2, g3, g4);

  // ---- Stage D: orientation + NMS + threshold; 4 outputs per thread.
  // dir_w[k] = center - neighbor_k; neighbor LDS offsets dr*MW+dc for
  // k=0..7: 1,37,36,35,-1,-37,-36,-35 (int8-packed). idx_neg = opposite.
  const int ty  = tid >> 3;         // 0..31
  const int tx0 = (tid & 7) << 2;   // 0..28 step 4
  const int base = (ty + 1) * MW + (tx0 + 1);
  const unsigned long long off_tbl = 0xDDDCDBFF23242501ULL;
  float res[4];
#pragma unroll
  for (int e = 0; e < 4; ++e) {
    float gxs = sm.gx[base + e];
    float gys = sm.gy[base + e];
    float mc  = sm.mg[base + e];
    float ori = atan2f(gys, gxs) * 57.295827908797776f + 180.0f;  // 180/3.14159
    int k = (int)rintf(ori / 45.0f);     // round-half-even like jnp.round
    int ip = k & 7;
    int off = (int)(signed char)(off_tbl >> (ip * 8));
    float csp = mc - sm.mg[base + e + off];
    float csn = mc - sm.mg[base + e - off];
    bool is_max = fminf(csp, csn) > 0.0f;
    bool keep = is_max && (mc >= 6.0f) && (mc <= 50.0f);
    res[e] = keep ? 1.0f : 0.0f;
  }
  *(float4*)&out[(size_t)(Y0 + ty) * IMG_W + (X0 + tx0)] =
      make_float4(res[0], res[1], res[2], res[3]);
}

extern "C" void kernel_launch(void* const* d_in, const int* in_sizes, int n_in,
                              void* d_out, int out_size, void* d_ws, size_t ws_size,
                              hipStream_t stream) {
  const float* img   = (const float*)d_in[0];
  const float* gauss = (const float*)d_in[1];
  float* out = (float*)d_out;
  dim3 grid(IMG_W / TW, IMG_H / TH);
  canny_fused<<<grid, 256, 0, stream>>>(img, gauss, out);
}

// Round 4
// 395.555 us; speedup vs baseline: 1.2232x; 1.2232x over previous
//
#include <hip/hip_runtime.h>

// Fused Canny-style edge pipeline, 1x3x4096x4096 fp32 -> 1x4096x4096 fp32.
// R4: per-pixel gx/gy/mag accumulated in REGISTERS across channels (stage-C
// task mapping == stage-D pixel mapping); only mag goes to LDS (NMS needs
// neighbors), with stride 37 (coprime 32) to kill bank conflicts. Halo ring
// of mag handled by 132 scalar tasks. LDS 17.2 KB.

#define IMG_H 4096
#define IMG_W 4096

constexpr int TW = 32, TH = 32;
constexpr int HBH = 40, HBW = 40;  // hblur: (r,c) -> abs (Y0-4+r, X0-2+c)
constexpr int BH  = 36, BW  = 40;  // blur:  (r,c) -> abs (Y0-2+r, X0-2+c)
constexpr int MH  = 34, MW  = 37;  // mag:   (r,c) -> abs (Y0-1+r, X0-1+c); cols 0..33 used

struct Smem {
  float hb[HBH * HBW];  // per-channel horizontal blur (transient)
  float bl[BH * BW];    // per-channel blurred (transient)
  float mg[MH * MW];    // grad_mag summed over channels (written once)
};

template <bool INTERIOR>
__device__ __forceinline__ void pipeline(Smem& sm, const float* __restrict__ img,
                                         float* __restrict__ out, int X0, int Y0,
                                         float g0, float g1, float g2, float g3, float g4) {
  const int tid = threadIdx.x;
  const int ty  = tid >> 3;         // 0..31: own output row
  const int tx0 = (tid & 7) << 2;   // 0..28: own output col group

  // Ring task: mag positions r in {0,33} x c in [1,32], plus c in {0,33} x r in [0,34).
  const bool has_ring = tid < 132;
  int rr_ = 0, rc_ = 0;
  if (tid < 64)        { rr_ = (tid < 32) ? 0 : 33; rc_ = 1 + (tid & 31); }
  else if (has_ring)   { int rem = tid - 64; rr_ = rem >> 1; rc_ = (rem & 1) ? 33 : 0; }

  float amg[4], agx[4], agy[4];  // own-pixel accumulators (sum over channels)
  float rmg = 0.f;               // ring mag accumulator

#pragma unroll
  for (int ch = 0; ch < 3; ++ch) {
    const float* im = img + (size_t)ch * ((size_t)IMG_H * IMG_W);

    // ---- Stage A: horizontal gaussian (40 rows x 10 groups of 4 cols).
    for (int j = tid; j < HBH * 10; j += 256) {
      int r = j / 10, g = j - r * 10, c0 = g * 4;
      float4 o;
      if (INTERIOR) {
        const float* row = im + (size_t)(Y0 - 4 + r) * IMG_W + (X0 - 4 + c0);
        float4 va = *(const float4*)row;
        float4 vb = *(const float4*)(row + 4);
        o.x = g0*va.x + g1*va.y + g2*va.z + g3*va.w + g4*vb.x;
        o.y = g0*va.y + g1*va.z + g2*va.w + g3*vb.x + g4*vb.y;
        o.z = g0*va.z + g1*va.w + g2*vb.x + g3*vb.y + g4*vb.z;
        o.w = g0*va.w + g1*vb.x + g2*vb.y + g3*vb.z + g4*vb.w;
      } else {
        int gy_ = Y0 - 4 + r;
        if ((unsigned)gy_ < IMG_H) {
          int cb = X0 - 4 + c0;
          const float* row = im + (size_t)gy_ * IMG_W;
          float t[8];
#pragma unroll
          for (int u = 0; u < 8; ++u) {
            int x = cb + u;
            t[u] = ((unsigned)x < IMG_W) ? row[x] : 0.f;
          }
          o.x = g0*t[0] + g1*t[1] + g2*t[2] + g3*t[3] + g4*t[4];
          o.y = g0*t[1] + g1*t[2] + g2*t[3] + g3*t[4] + g4*t[5];
          o.z = g0*t[2] + g1*t[3] + g2*t[4] + g3*t[5] + g4*t[6];
          o.w = g0*t[3] + g1*t[4] + g2*t[5] + g3*t[6] + g4*t[7];
        } else {
          o = make_float4(0.f, 0.f, 0.f, 0.f);
        }
      }
      *(float4*)&sm.hb[r * HBW + c0] = o;
    }
    __syncthreads();

    // ---- Stage B: vertical gaussian (36 rows x 10 groups).
    for (int j = tid; j < BH * 10; j += 256) {
      int r = j / 10, g = j - r * 10, c0 = g * 4;
      float4 a0 = *(const float4*)&sm.hb[(r    ) * HBW + c0];
      float4 a1 = *(const float4*)&sm.hb[(r + 1) * HBW + c0];
      float4 a2 = *(const float4*)&sm.hb[(r + 2) * HBW + c0];
      float4 a3 = *(const float4*)&sm.hb[(r + 3) * HBW + c0];
      float4 a4 = *(const float4*)&sm.hb[(r + 4) * HBW + c0];
      float4 v;
      v.x = g0*a0.x + g1*a1.x + g2*a2.x + g3*a3.x + g4*a4.x;
      v.y = g0*a0.y + g1*a1.y + g2*a2.y + g3*a3.y + g4*a4.y;
      v.z = g0*a0.z + g1*a1.z + g2*a2.z + g3*a3.z + g4*a4.z;
      v.w = g0*a0.w + g1*a1.w + g2*a2.w + g3*a3.w + g4*a4.w;
      if (!INTERIOR) {
        // Force exact 0 outside image: the Sobel conv zero-pads *blurred*.
        int gy_ = Y0 - 2 + r;
        bool rok = (unsigned)gy_ < IMG_H;
        int gx0 = X0 - 2 + c0;
        v.x = (rok && (unsigned)(gx0    ) < IMG_W) ? v.x : 0.f;
        v.y = (rok && (unsigned)(gx0 + 1) < IMG_W) ? v.y : 0.f;
        v.z = (rok && (unsigned)(gx0 + 2) < IMG_W) ? v.z : 0.f;
        v.w = (rok && (unsigned)(gx0 + 3) < IMG_W) ? v.w : 0.f;
      }
      *(float4*)&sm.bl[r * BW + c0] = v;
    }
    __syncthreads();

    // ---- Stage C (inner): own pixels. mag row ty+1 uses bl rows ty+1..ty+3,
    // cols tx0+1..tx0+6 (aligned float4 pair covers tx0..tx0+7).
    {
      float w0[8], w1[8], w2[8];
      {
        const int b = (ty + 1) * BW + tx0;
        *(float4*)&w0[0] = *(const float4*)&sm.bl[b];
        *(float4*)&w0[4] = *(const float4*)&sm.bl[b + 4];
        *(float4*)&w1[0] = *(const float4*)&sm.bl[b + BW];
        *(float4*)&w1[4] = *(const float4*)&sm.bl[b + BW + 4];
        *(float4*)&w2[0] = *(const float4*)&sm.bl[b + 2 * BW];
        *(float4*)&w2[4] = *(const float4*)&sm.bl[b + 2 * BW + 4];
      }
#pragma unroll
      for (int e = 0; e < 4; ++e) {
        float gxv = w0[e+1] - w0[e+3] + 2.f * w1[e+1] - 2.f * w1[e+3] + w2[e+1] - w2[e+3];
        float gyv = w0[e+1] + 2.f * w0[e+2] + w0[e+3] - w2[e+1] - 2.f * w2[e+2] - w2[e+3];
        float m = sqrtf(gxv * gxv + gyv * gyv + 1e-8f);
        // own pixels are always inside the image -> no mask even on edge blocks
        if (ch == 0) { amg[e] = m;  agx[e] = gxv;  agy[e] = gyv; }
        else         { amg[e] += m; agx[e] += gxv; agy[e] += gyv; }
      }
    }

    // ---- Stage C (ring): one scalar mag per thread for the NMS halo.
    if (has_ring) {
      const int b = rr_ * BW + rc_;
      float v00 = sm.bl[b         ], v01 = sm.bl[b + 1         ], v02 = sm.bl[b + 2         ];
      float v10 = sm.bl[b + BW    ],                              v12 = sm.bl[b + BW + 2    ];
      float v20 = sm.bl[b + 2*BW  ], v21 = sm.bl[b + 2*BW + 1  ], v22 = sm.bl[b + 2*BW + 2 ];
      float gxv = v00 - v02 + 2.f * v10 - 2.f * v12 + v20 - v22;
      float gyv = v00 + 2.f * v01 + v02 - v20 - 2.f * v21 - v22;
      float m = sqrtf(gxv * gxv + gyv * gyv + 1e-8f);
      if (!INTERIOR) {
        int gyy = Y0 - 1 + rr_, gxx = X0 - 1 + rc_;
        m = ((unsigned)gyy < IMG_H && (unsigned)gxx < IMG_W) ? m : 0.f;
      }
      if (ch == 0) rmg = m; else rmg += m;
    }
    // No barrier needed here: next A writes hb (untouched by C); next B's bl
    // write is fenced by the sync after A.
  }

  // ---- Publish mag to LDS (once), then NMS.
  {
    const int b = (ty + 1) * MW + tx0 + 1;
#pragma unroll
    for (int e = 0; e < 4; ++e) sm.mg[b + e] = amg[e];
    if (has_ring) sm.mg[rr_ * MW + rc_] = rmg;
  }
  __syncthreads();

  // ---- Stage D: orientation + NMS + threshold; 4 outputs per thread.
  // dir_w[k] = center - neighbor_k; neighbor LDS offsets dr*MW+dc for
  // k=0..7: 1,38,37,36,-1,-38,-37,-36 (int8-packed). idx_neg = opposite.
  const int base = (ty + 1) * MW + tx0 + 1;
  const unsigned long long off_tbl = 0xDCDBDAFF24252601ULL;
  float res[4];
#pragma unroll
  for (int e = 0; e < 4; ++e) {
    float gxs = agx[e];
    float gys = agy[e];
    float mc  = amg[e];
    float ori = atan2f(gys, gxs) * 57.295827908797776f + 180.0f;  // 180/3.14159
    int k = (int)rintf(ori / 45.0f);     // round-half-even like jnp.round
    int ip = k & 7;
    int off = (int)(signed char)(off_tbl >> (ip * 8));
    float csp = mc - sm.mg[base + e + off];
    float csn = mc - sm.mg[base + e - off];
    bool is_max = fminf(csp, csn) > 0.0f;
    bool keep = is_max && (mc >= 6.0f) && (mc <= 50.0f);
    res[e] = keep ? 1.0f : 0.0f;
  }
  *(float4*)&out[(size_t)(Y0 + ty) * IMG_W + (X0 + tx0)] =
      make_float4(res[0], res[1], res[2], res[3]);
}

__global__ __launch_bounds__(256, 6)
void canny_fused(const float* __restrict__ img,
                 const float* __restrict__ gauss,
                 float* __restrict__ out) {
  __shared__ Smem sm;
  const int X0 = blockIdx.x * TW;
  const int Y0 = blockIdx.y * TH;
  const float g0 = gauss[0], g1 = gauss[1], g2 = gauss[2],
              g3 = gauss[3], g4 = gauss[4];
  const bool interior = (X0 >= 4) && (X0 + 40 <= IMG_W) &&
                        (Y0 >= 4) && (Y0 + 36 <= IMG_H);
  if (interior) pipeline<true >(sm, img, out, X0, Y0, g0, g1, g2, g3, g4);
  else          pipeline<false>(sm, img, out, X0, Y0, g0, g1, g2, g3, g4);
}

extern "C" void kernel_launch(void* const* d_in, const int* in_sizes, int n_in,
                              void* d_out, int out_size, void* d_ws, size_t ws_size,
                              hipStream_t stream) {
  const float* img   = (const float*)d_in[0];
  const float* gauss = (const float*)d_in[1];
  float* out = (float*)d_out;
  dim3 grid(IMG_W / TW, IMG_H / TH);
  canny_fused<<<grid, 256, 0, stream>>>(img, gauss, out);
}